// Round 1
// 14042.189 us; speedup vs baseline: 1.6395x; 1.6395x over previous
//
#include <hip/hip_runtime.h>
#include <stdint.h>

typedef unsigned short u16;
typedef unsigned long long ull;
typedef __attribute__((ext_vector_type(8))) short bf16x8;
typedef __attribute__((ext_vector_type(4))) float f32x4;

#define MFMA_BF16 __builtin_amdgcn_mfma_f32_16x16x32_bf16

// ---------- small helpers ----------
__device__ __forceinline__ u16 f2bf(float f) {
  union { float f; unsigned u; } v; v.f = f;
  unsigned r = v.u + 0x7FFFu + ((v.u >> 16) & 1u);
  return (u16)(r >> 16);
}
__device__ __forceinline__ float fsig(float x) {
  return __fdividef(1.0f, 1.0f + __expf(-x));
}
__device__ __forceinline__ float ftanh(float x) {
  x = fminf(15.0f, fmaxf(-15.0f, x));
  float a = __expf(2.0f * x);
  return __fdividef(a - 1.0f, a + 1.0f);
}
__device__ __forceinline__ bf16x8 ldg8(const u16* p) { return *(const bf16x8*)p; }

// Fence-free device barrier among 16 co-resident wgs.
// Per-wg epoch slot (64B apart). NO acquire/release fences -> no buffer_inv/
// buffer_wbl2 -> L2 stays resident. All cross-wg data moves via RELAXED AGENT
// (sc0 sc1, coherent-point) loads/stores; the vmcnt(0) drain that
// __syncthreads emits makes those stores globally visible before the arrival
// store issues.
__device__ __forceinline__ void dev_barrier(unsigned* slots, unsigned epoch, int wg) {
  __threadfence_block();   // belt-and-braces: drain this wave's vmem ops
  __syncthreads();         // all waves drained (compiler emits vmcnt(0) before s_barrier)
  if (threadIdx.x < 64) {
    if (threadIdx.x == 0)
      __hip_atomic_store(slots + (size_t)wg * 16, epoch,
                         __ATOMIC_RELAXED, __HIP_MEMORY_SCOPE_AGENT);
    const int sl = (threadIdx.x < 16) ? (int)threadIdx.x : 0;
    while (true) {
      const unsigned v = __hip_atomic_load(slots + (size_t)sl * 16,
                                           __ATOMIC_RELAXED, __HIP_MEMORY_SCOPE_AGENT);
      if (__all(v >= epoch)) break;
      __builtin_amdgcn_s_sleep(2);
    }
  }
  __syncthreads();
}

// ---------- workspace layout (element offsets) ----------
enum : size_t {
  WB_WIH_F = 0,
  WB_WHH_F = WB_WIH_F + 2048ull * 512,
  WB_WIH_B = WB_WHH_F + 2048ull * 512,
  WB_WHH_B = WB_WIH_B + 2048ull * 512,
  WB_WIH_D = WB_WHH_B + 2048ull * 512,
  WB_WHH_D = WB_WIH_D + 2048ull * 2048,
  WB_WBR   = WB_WHH_D + 2048ull * 512,
  WB_WEK   = WB_WBR + 512ull * 1024,
  WB_WRO   = WB_WEK + 512ull * 1024,
  WB_WRD   = WB_WRO + 512ull * 1536,
  WB_EMBT  = WB_WRD + 32000ull * 512,
  WB_ATTR  = WB_EMBT + 2048ull * 512,
  WB_XENC  = WB_ATTR + 128ull * 512,
  WB_DCAT  = WB_XENC + 2048ull * 1024,
  WB_STATE = WB_DCAT + 128ull * 1024,
  WB_PRES  = WB_STATE + 2ull * 16 * 1536,
  WB_END   = WB_PRES + 2048ull * 512,
};
enum : size_t {
  F_XG_F   = 0,
  F_XG_B   = F_XG_F + 2048ull * 2048,
  F_XG_D   = F_XG_B + 2048ull * 2048,
  F_DCONST = F_XG_D + 2048ull * 2048,
  F_XENCF  = F_DCONST + 16ull * 2048,        // unused now (ctx reads bf16)
  F_XENCK  = F_XENCF + 2048ull * 1024,
  F_DECINIT= F_XENCK + 2048ull * 512,
  F_PROJP  = F_DECINIT + 16ull * 512,
  F_END    = F_PROJP + 16ull * 16 * 512,
};

// ---------- weight f32 -> bf16 conversion ----------
__global__ __launch_bounds__(256)
void convert_weights(const float* __restrict__ s0, const float* __restrict__ s1,
                     const float* __restrict__ s2, const float* __restrict__ s3,
                     const float* __restrict__ s4, const float* __restrict__ s5,
                     const float* __restrict__ s6, const float* __restrict__ s7,
                     const float* __restrict__ s8, const float* __restrict__ s9,
                     u16* __restrict__ dst)
{
  const float* srcs[10] = {s0, s1, s2, s3, s4, s5, s6, s7, s8, s9};
  const int sizes[10] = {1048576, 1048576, 1048576, 1048576, 4194304,
                         1048576, 524288, 524288, 786432, 16384000};
  size_t off = 0;
  const int stride = gridDim.x * blockDim.x;
  const int tid0 = blockIdx.x * blockDim.x + threadIdx.x;
  for (int m = 0; m < 10; ++m) {
    const float* s = srcs[m];
    const int n = sizes[m];
    for (int i = tid0; i < n; i += stride) dst[off + i] = f2bf(s[i]);
    off += n;
  }
}

// ---------- embedding gather (time-major) + attr sum ----------
__global__ __launch_bounds__(256)
void gather_kernel(const int* __restrict__ x_train, const int* __restrict__ y_train,
                   const float* __restrict__ word_emb, const float* __restrict__ attr_emb,
                   u16* __restrict__ embT, u16* __restrict__ attrb)
{
  const int wg = blockIdx.x, tid = threadIdx.x;
  if (wg < 2048) {               // embT[t*16+b][e] = word_emb[x_train[b][t]][e]
    const int t = wg >> 4, b = wg & 15;
    const int tok = x_train[b * 128 + t];
    const float* src = word_emb + (size_t)tok * 512;
    u16* dst = embT + (size_t)wg * 512;
    for (int e = tid; e < 512; e += 256) dst[e] = f2bf(src[e]);
  } else {                       // attr[b] = sum_ly attr_emb[y_train[b][ly]]
    const int b = wg - 2048;
    const int t0 = y_train[b * 2], t1 = y_train[b * 2 + 1];
    const float* a0 = attr_emb + (size_t)t0 * 512;
    const float* a1 = attr_emb + (size_t)t1 * 512;
    u16* dst = attrb + (size_t)b * 512;
    for (int e = tid; e < 512; e += 256) dst[e] = f2bf(a0[e] + a1[e]);
  }
}

// ---------- generic C = A * B^T GEMM, bf16 MFMA, f32 out ----------
#define LDP 40
__global__ __launch_bounds__(256)
void gemm_bt(const u16* __restrict__ A, const u16* __restrict__ B, float* __restrict__ C,
             int N, int K, int lda, int ldb,
             const float* __restrict__ bias1, const float* __restrict__ bias2,
             int mode, int Mlog)
{
  __shared__ u16 sA[128 * LDP];
  __shared__ u16 sB[128 * LDP];
  const int tid = threadIdx.x;
  const int nb = N >> 7;
  const int bm = blockIdx.x / nb, bn = blockIdx.x % nb;
  const int row0 = bm << 7, col0 = bn << 7;
  const int wave = tid >> 6, lane = tid & 63;
  const int wm = (wave >> 1) << 6, wn = (wave & 1) << 6;
  const int r = lane & 15, q = lane >> 4;
  const f32x4 zero = {0.f, 0.f, 0.f, 0.f};
  f32x4 acc[4][4];
  #pragma unroll
  for (int i = 0; i < 4; ++i)
    #pragma unroll
    for (int j = 0; j < 4; ++j) acc[i][j] = zero;

  const int arow = tid >> 2, ak = (tid & 3) << 3;
  const u16* Ag  = A + (size_t)(row0 + arow) * lda + ak;
  const u16* Ag2 = A + (size_t)(row0 + arow + 64) * lda + ak;
  const u16* Bg  = B + (size_t)(col0 + arow) * ldb + ak;
  const u16* Bg2 = B + (size_t)(col0 + arow + 64) * ldb + ak;
  u16* sAw  = sA + arow * LDP + ak;
  u16* sAw2 = sA + (arow + 64) * LDP + ak;
  u16* sBw  = sB + arow * LDP + ak;
  u16* sBw2 = sB + (arow + 64) * LDP + ak;

  for (int kt = 0; kt < K; kt += 32) {
    bf16x8 a0 = ldg8(Ag + kt), a1 = ldg8(Ag2 + kt);
    bf16x8 b0 = ldg8(Bg + kt), b1 = ldg8(Bg2 + kt);
    __syncthreads();
    *(bf16x8*)sAw = a0; *(bf16x8*)sAw2 = a1;
    *(bf16x8*)sBw = b0; *(bf16x8*)sBw2 = b1;
    __syncthreads();
    bf16x8 af[4], bfv[4];
    #pragma unroll
    for (int i = 0; i < 4; ++i) af[i]  = ldg8(sA + (wm + 16 * i + r) * LDP + (q << 3));
    #pragma unroll
    for (int j = 0; j < 4; ++j) bfv[j] = ldg8(sB + (wn + 16 * j + r) * LDP + (q << 3));
    #pragma unroll
    for (int i = 0; i < 4; ++i)
      #pragma unroll
      for (int j = 0; j < 4; ++j)
        acc[i][j] = MFMA_BF16(af[i], bfv[j], acc[i][j], 0, 0, 0);
  }

  #pragma unroll
  for (int j = 0; j < 4; ++j) {
    const int gcol = col0 + wn + 16 * j + r;
    float bv = 0.f;
    if (bias1) bv += bias1[gcol];
    if (bias2) bv += bias2[gcol];
    #pragma unroll
    for (int i = 0; i < 4; ++i) {
      const int growb = row0 + wm + 16 * i + (q << 2);
      #pragma unroll
      for (int v = 0; v < 4; ++v) {
        const int grow = growb + v;
        if (grow >= Mlog) continue;
        const float val = acc[i][j][v] + bv;
        if (mode == 0) {
          C[(size_t)grow * N + gcol] = val;
        } else {
          const int tt = grow >> 4, bb = grow & 15;
          if (tt < 127) C[((size_t)bb * 127 + tt) * 32000 + gcol] = val;
        }
      }
    }
  }
}

// ---------- encoder: both LSTM directions, persistent, 1 barrier/step ----------
// Cross-wg h exchange via RELAXED AGENT ull ops; prev-h staged once into LDS.
__global__ __launch_bounds__(256)
void encoder_kernel(const float* __restrict__ xg_f, const float* __restrict__ xg_b,
                    const u16* __restrict__ Whh_f_bf, const u16* __restrict__ Whh_b_bf,
                    u16* __restrict__ x_enc_bf, u16* __restrict__ dec_cat_bf,
                    unsigned* __restrict__ slots_base)
{
  const int wgid = blockIdx.x;
  const int dir = wgid >> 4;
  const int g = wgid & 15, s = g * 32;
  const float* xg = dir ? xg_b : xg_f;
  const u16* Whh = dir ? Whh_b_bf : Whh_f_bf;
  unsigned* slots = slots_base + (size_t)dir * 256;
  const int tid = threadIdx.x, wave = tid >> 6, lane = tid & 63;
  const int r = lane & 15, q = lane >> 4;
  __shared__ u16 sH[16 * 520];     // prev h (this dir), +8 pad -> 2-way-free banks
  __shared__ float gact[4][16][32];
  __shared__ float c_sl[16][32];
  __shared__ float h_sl[16][32];

  ((float*)c_sl)[tid] = 0.f;
  ((float*)c_sl)[tid + 256] = 0.f;

  const int colbase = wave * 512 + s;  // gate chunk = wave
  for (int step = 0; step < 128; ++step) {
    const int t = dir ? (127 - step) : step;
    const int tprev = dir ? (t + 1) : (t - 1);
    if (step > 0) {   // stage prev-h (16 x 512 bf16) into LDS, coherent reads
      #pragma unroll
      for (int i2 = 0; i2 < 8; ++i2) {
        const int i = tid + i2 * 256;            // 0..2047 (16 rows x 128 ull)
        const int row = i >> 7, cu = i & 127;
        const ull v = __hip_atomic_load(
            (const ull*)(x_enc_bf + ((size_t)(tprev * 16 + row)) * 1024 + dir * 512) + cu,
            __ATOMIC_RELAXED, __HIP_MEMORY_SCOPE_AGENT);
        *((ull*)(sH + row * 520) + cu) = v;
      }
    }
    __syncthreads();
    f32x4 acc0 = {0.f, 0.f, 0.f, 0.f}, acc1 = {0.f, 0.f, 0.f, 0.f};
    if (step > 0) {
      const u16* Aq = sH + r * 520 + q * 8;
      const u16* B0 = Whh + (size_t)(colbase + r) * 512 + q * 8;
      const u16* B1 = Whh + (size_t)(colbase + 16 + r) * 512 + q * 8;
      #pragma unroll
      for (int kt = 0; kt < 16; ++kt) {
        bf16x8 af = ldg8(Aq + kt * 32);
        acc0 = MFMA_BF16(af, ldg8(B0 + kt * 32), acc0, 0, 0, 0);
        acc1 = MFMA_BF16(af, ldg8(B1 + kt * 32), acc1, 0, 0, 0);
      }
    }
    #pragma unroll
    for (int v = 0; v < 4; ++v) {
      const int b = q * 4 + v;
      const float* xrow = xg + (size_t)(t * 16 + b) * 2048;
      float g0 = acc0[v] + xrow[colbase + r];
      float g1 = acc1[v] + xrow[colbase + 16 + r];
      if (wave == 2) { g0 = ftanh(g0); g1 = ftanh(g1); }
      else           { g0 = fsig(g0);  g1 = fsig(g1);  }
      gact[wave][b][r] = g0;
      gact[wave][b][16 + r] = g1;
    }
    __syncthreads();
    #pragma unroll
    for (int e2 = 0; e2 < 2; ++e2) {
      const int e = tid + e2 * 256;
      const int b = e >> 5, dl = e & 31;
      float c = gact[1][b][dl] * c_sl[b][dl] + gact[0][b][dl] * gact[2][b][dl];
      c_sl[b][dl] = c;
      h_sl[b][dl] = gact[3][b][dl] * ftanh(c);
    }
    __syncthreads();
    if (tid < 128) {   // pack 4 bf16 -> coherent ull store of h
      const int b = tid >> 3, d4 = (tid & 7) << 2;
      union { u16 h4[4]; ull u; } pk;
      #pragma unroll
      for (int k = 0; k < 4; ++k) pk.h4[k] = f2bf(h_sl[b][d4 + k]);
      __hip_atomic_store(
          (ull*)(x_enc_bf + ((size_t)(t * 16 + b)) * 1024 + dir * 512 + s) + (tid & 7),
          pk.u, __ATOMIC_RELAXED, __HIP_MEMORY_SCOPE_AGENT);
    }
    dev_barrier(slots, (unsigned)(step + 1), g);
  }
  // final cell state -> concat(cTf, cTb)   (read after kernel end: ordinary store)
  #pragma unroll
  for (int e2 = 0; e2 < 2; ++e2) {
    const int e = tid + e2 * 256;
    const int b = e >> 5, dl = e & 31;
    dec_cat_bf[b * 1024 + dir * 512 + s + dl] = f2bf(c_sl[b][dl]);
  }
}

// ---------- decoder init: state buf0 = [tanh(c0) | zeros] ----------
__global__ __launch_bounds__(256)
void decinit_kernel(const float* __restrict__ dec_init, u16* __restrict__ state_bf)
{
  const int idx = blockIdx.x * 256 + threadIdx.x;
  if (idx >= 16 * 1536) return;
  const int b = idx / 1536, j = idx % 1536;
  state_bf[idx] = (j < 512) ? f2bf(ftanh(dec_init[b * 512 + j])) : (u16)0;
}

// ---------- decoder: persistent, 16 wgs x 1024 thr, 2 barriers/step ----------
// State staged once per step into LDS via coherent loads; all cross-wg traffic
// RELAXED AGENT; weights stay L2-resident (no fences).
__global__ __launch_bounds__(1024)
void decoder_kernel(const float* __restrict__ xg_d, const float* __restrict__ dec_const,
                    const u16* __restrict__ Whh_d_bf, const u16* __restrict__ Wih_d_bf,
                    const u16* __restrict__ W_ro_bf,
                    const float* __restrict__ W_trg, const float* __restrict__ b_trg,
                    const float* __restrict__ w_att, const float* __restrict__ b_att,
                    const float* __restrict__ x_enc_k, const u16* __restrict__ x_enc_bf,
                    const float* __restrict__ dec_init,
                    u16* __restrict__ state_bf, float* __restrict__ proj_part,
                    u16* __restrict__ pres_bf, unsigned* __restrict__ slots)
{
  const int wg = blockIdx.x;   // 0..15
  const int tid = threadIdx.x;
  const int wave = tid >> 6, lane = tid & 63;
  const int r = lane & 15, q = lane >> 4;
  const int s = wg * 32;

  __shared__ u16 sState[16 * 1544];  // [h(512)|feed(1024)] per b, +8 pad
  __shared__ float gact[4][16][32];
  __shared__ float h_sl[16][32];
  __shared__ float c_sl[16][32];
  __shared__ float proj_s[512];
  __shared__ float sc_s[128];
  __shared__ float w_s[128];

  if (tid < 512) {
    const int b = tid >> 5, dl = tid & 31;
    c_sl[b][dl] = dec_init[b * 512 + s + dl];
  }

  for (int t = 0; t <= 127; ++t) {
    const int cur = t & 1, nxt = cur ^ 1;
    const u16* st = state_bf + (size_t)cur * (16 * 1536);
    u16* stn = state_bf + (size_t)nxt * (16 * 1536);

    // -------- stage state (16x1536 bf16 = 6144 ull) into LDS, coherent --------
    {
      const ull* stu = (const ull*)st;
      #pragma unroll
      for (int i2 = 0; i2 < 6; ++i2) {
        const int i = tid + i2 * 1024;
        const int row = i / 384, cu = i - row * 384;
        const ull v = __hip_atomic_load(stu + i, __ATOMIC_RELAXED, __HIP_MEMORY_SCOPE_AGENT);
        *((ull*)(sState + row * 1544) + cu) = v;
      }
    }
    __syncthreads();

    // -------- P1 --------
    if (t < 127 && wave < 8) {
      const int j = wave;
      const int chunk = j >> 1;
      const int colbase = chunk * 512 + s + 16 * (j & 1);
      const int gcol_row = colbase + r;
      f32x4 acc = {0.f, 0.f, 0.f, 0.f};
      const u16* Aq = sState + r * 1544 + q * 8;
      const u16* B1 = Whh_d_bf + (size_t)gcol_row * 512 + q * 8;
      const u16* B2 = Wih_d_bf + (size_t)gcol_row * 2048 + 1024 + q * 8;
      #pragma unroll
      for (int kt = 0; kt < 16; ++kt)   // h part, K=512
        acc = MFMA_BF16(ldg8(Aq + kt * 32), ldg8(B1 + kt * 32), acc, 0, 0, 0);
      #pragma unroll
      for (int kt = 0; kt < 32; ++kt)   // feed part, K=1024
        acc = MFMA_BF16(ldg8(Aq + 512 + kt * 32), ldg8(B2 + kt * 32), acc, 0, 0, 0);
      #pragma unroll
      for (int v = 0; v < 4; ++v) {
        const int b = q * 4 + v;
        const int col = colbase + r;
        const float gval = acc[v] + xg_d[(size_t)(t * 16 + b) * 2048 + col]
                                  + dec_const[b * 2048 + col];
        const float a = (chunk == 2) ? ftanh(gval) : fsig(gval);
        gact[chunk][b][16 * (j & 1) + r] = a;
      }
    } else if (t > 0 && (wave == 8 || wave == 9)) {
      // pres[t-1] = tanh([h,ctx] @ W_ro^T); depends only on state_{t-1}
      const int col = s + 16 * (wave - 8) + r;
      f32x4 acc = {0.f, 0.f, 0.f, 0.f};
      const u16* Aq = sState + r * 1544 + q * 8;
      const u16* Bq = W_ro_bf + (size_t)col * 1536 + q * 8;
      #pragma unroll
      for (int kt = 0; kt < 48; ++kt)
        acc = MFMA_BF16(ldg8(Aq + kt * 32), ldg8(Bq + kt * 32), acc, 0, 0, 0);
      #pragma unroll
      for (int v = 0; v < 4; ++v) {
        const int b = q * 4 + v;
        pres_bf[(size_t)((t - 1) * 16 + b) * 512 + col] = f2bf(ftanh(acc[v]));
      }
    }
    __syncthreads();
    if (t < 127 && tid < 512) {   // c/h update for this wg's 32 dims
      const int b = tid >> 5, dl = tid & 31;
      float c = gact[1][b][dl] * c_sl[b][dl] + gact[0][b][dl] * gact[2][b][dl];
      c_sl[b][dl] = c;
      h_sl[b][dl] = gact[3][b][dl] * ftanh(c);
    }
    __syncthreads();
    if (t < 127) {
      if (tid < 128) {   // pack h -> coherent ull store into next state
        const int b = tid >> 3, d4 = (tid & 7) << 2;
        union { u16 h4[4]; ull u; } pk;
        #pragma unroll
        for (int k = 0; k < 4; ++k) pk.h4[k] = f2bf(h_sl[b][d4 + k]);
        __hip_atomic_store((ull*)(stn + (size_t)b * 1536 + s) + (tid & 7), pk.u,
                           __ATOMIC_RELAXED, __HIP_MEMORY_SCOPE_AGENT);
      }
      // proj partial: h_slice @ W_trg[:, s:s+32]^T  (coherent f32 stores)
      #pragma unroll
      for (int ii = 0; ii < 8; ++ii) {
        const int o = tid + ii * 1024;
        const int b = o >> 9, p = o & 511;
        const float* wrow = W_trg + (size_t)p * 512 + s;
        float a2 = 0.f;
        #pragma unroll
        for (int dl = 0; dl < 32; ++dl) a2 += h_sl[b][dl] * wrow[dl];
        __hip_atomic_store(proj_part + (size_t)wg * 8192 + b * 512 + p, a2,
                           __ATOMIC_RELAXED, __HIP_MEMORY_SCOPE_AGENT);
      }
    }
    dev_barrier(slots, (unsigned)(2 * t + 1), wg);

    // -------- P2 (wg acts as batch row b) --------
    if (t < 127) {
      const int b = wg;
      if (tid < 512) {
        float v = b_trg[tid];
        #pragma unroll
        for (int p2 = 0; p2 < 16; ++p2)
          v += __hip_atomic_load(proj_part + (size_t)p2 * 8192 + b * 512 + tid,
                                 __ATOMIC_RELAXED, __HIP_MEMORY_SCOPE_AGENT);
        proj_s[tid] = v;
      }
      __syncthreads();
      {  // scores: wave w -> l in [8w, 8w+8)
        float wv[8];
        const float* wap = w_att + lane * 8;
        #pragma unroll
        for (int jj = 0; jj < 8; ++jj) wv[jj] = wap[jj];
        for (int li = 0; li < 8; ++li) {
          const int l = wave * 8 + li;
          const float* xk = x_enc_k + (size_t)(l * 16 + b) * 512 + lane * 8;
          float a3 = 0.f;
          #pragma unroll
          for (int jj = 0; jj < 8; ++jj)
            a3 += wv[jj] * ftanh(xk[jj] + proj_s[lane * 8 + jj]);
          #pragma unroll
          for (int off = 32; off; off >>= 1) a3 += __shfl_xor(a3, off);
          if (lane == 0) sc_s[l] = a3 + b_att[0];
        }
      }
      __syncthreads();
      if (wave == 0) {  // softmax over 128 scores
        const float s0 = sc_s[lane], s1 = sc_s[lane + 64];
        float m = fmaxf(s0, s1);
        #pragma unroll
        for (int off = 32; off; off >>= 1) m = fmaxf(m, __shfl_xor(m, off));
        const float e0 = __expf(s0 - m), e1 = __expf(s1 - m);
        float sum = e0 + e1;
        #pragma unroll
        for (int off = 32; off; off >>= 1) sum += __shfl_xor(sum, off);
        const float inv = __fdividef(1.0f, sum);
        w_s[lane] = e0 * inv;
        w_s[lane + 64] = e1 * inv;
      }
      __syncthreads();
      if (tid < 512) {  // ctx from bf16 x_enc pairs -> coherent feed store
        float al = 0.f, ah = 0.f;
        const unsigned* xe = (const unsigned*)x_enc_bf + (size_t)b * 512 + tid;
        #pragma unroll 8
        for (int l = 0; l < 128; ++l) {
          const unsigned vv = xe[(size_t)l * 8192];
          union { unsigned u; float f; } lo, hi;
          lo.u = vv << 16; hi.u = vv & 0xFFFF0000u;
          const float wl = w_s[l];
          al += wl * lo.f; ah += wl * hi.f;
        }
        const unsigned pk = (unsigned)f2bf(al) | ((unsigned)f2bf(ah) << 16);
        __hip_atomic_store((unsigned*)(stn + (size_t)b * 1536 + 512) + tid, pk,
                           __ATOMIC_RELAXED, __HIP_MEMORY_SCOPE_AGENT);
      }
    }
    dev_barrier(slots, (unsigned)(2 * t + 2), wg);
  }
}

// ---------- host launch ----------
extern "C" void kernel_launch(void* const* d_in, const int* in_sizes, int n_in,
                              void* d_out, int out_size, void* d_ws, size_t ws_size,
                              hipStream_t stream)
{
  const int*   x_train  = (const int*)d_in[0];
  const int*   y_train  = (const int*)d_in[2];
  const float* word_emb = (const float*)d_in[3];
  const float* attr_emb = (const float*)d_in[4];
  const float* Wih_f = (const float*)d_in[5];
  const float* Whh_f = (const float*)d_in[6];
  const float* bih_f = (const float*)d_in[7];
  const float* bhh_f = (const float*)d_in[8];
  const float* Wih_b = (const float*)d_in[9];
  const float* Whh_b = (const float*)d_in[10];
  const float* bih_b = (const float*)d_in[11];
  const float* bhh_b = (const float*)d_in[12];
  const float* W_bridge = (const float*)d_in[13];
  const float* W_enc2k  = (const float*)d_in[14];
  const float* Wih_d = (const float*)d_in[15];
  const float* Whh_d = (const float*)d_in[16];
  const float* bih_d = (const float*)d_in[17];
  const float* bhh_d = (const float*)d_in[18];
  const float* W_trg = (const float*)d_in[19];
  const float* b_trg = (const float*)d_in[20];
  const float* w_att = (const float*)d_in[21];
  const float* b_att = (const float*)d_in[22];
  const float* W_ro  = (const float*)d_in[23];
  const float* W_read= (const float*)d_in[24];
  float* out = (float*)d_out;

  char* ws = (char*)d_ws;
  unsigned* barriers = (unsigned*)ws;                        // 4 KiB of epoch slots
  u16* bfa = (u16*)(ws + 4096);
  float* fa = (float*)(ws + 4096 + (size_t)WB_END * 2);
  const size_t need = 4096 + (size_t)WB_END * 2 + (size_t)F_END * 4;
  if (ws_size < need) return;   // workspace too small; fail loudly via mismatch

  hipMemsetAsync(barriers, 0, 4096, stream);

  convert_weights<<<dim3(1024), dim3(256), 0, stream>>>(
      Wih_f, Whh_f, Wih_b, Whh_b, Wih_d, Whh_d, W_bridge, W_enc2k, W_ro, W_read, bfa);

  gather_kernel<<<dim3(2064), dim3(256), 0, stream>>>(
      x_train, y_train, word_emb, attr_emb, bfa + WB_EMBT, bfa + WB_ATTR);

  // G1: xg_f = embT @ Wih_f^T + (bih_f + bhh_f)
  gemm_bt<<<dim3(16 * 16), dim3(256), 0, stream>>>(
      bfa + WB_EMBT, bfa + WB_WIH_F, fa + F_XG_F, 2048, 512, 512, 512, bih_f, bhh_f, 0, 2048);
  // G2: xg_b
  gemm_bt<<<dim3(16 * 16), dim3(256), 0, stream>>>(
      bfa + WB_EMBT, bfa + WB_WIH_B, fa + F_XG_B, 2048, 512, 512, 512, bih_b, bhh_b, 0, 2048);
  // G3: xg_d = embT @ Wih_d[:, :512]^T + (bih_d + bhh_d)
  gemm_bt<<<dim3(16 * 16), dim3(256), 0, stream>>>(
      bfa + WB_EMBT, bfa + WB_WIH_D, fa + F_XG_D, 2048, 512, 512, 2048, bih_d, bhh_d, 0, 2048);
  // G4: dec_const = attr @ Wih_d[:, 512:1024]^T
  gemm_bt<<<dim3(1 * 16), dim3(256), 0, stream>>>(
      bfa + WB_ATTR, bfa + WB_WIH_D + 512, fa + F_DCONST, 2048, 512, 512, 2048,
      nullptr, nullptr, 0, 16);

  encoder_kernel<<<dim3(32), dim3(256), 0, stream>>>(
      fa + F_XG_F, fa + F_XG_B, bfa + WB_WHH_F, bfa + WB_WHH_B,
      bfa + WB_XENC, bfa + WB_DCAT, barriers + 256);

  // G6: x_enc_k = x_enc @ W_enc2k^T
  gemm_bt<<<dim3(16 * 4), dim3(256), 0, stream>>>(
      bfa + WB_XENC, bfa + WB_WEK, fa + F_XENCK, 512, 1024, 1024, 1024,
      nullptr, nullptr, 0, 2048);
  // G5: dec_init = cat(cTf,cTb) @ W_bridge^T
  gemm_bt<<<dim3(1 * 4), dim3(256), 0, stream>>>(
      bfa + WB_DCAT, bfa + WB_WBR, fa + F_DECINIT, 512, 1024, 1024, 1024,
      nullptr, nullptr, 0, 16);

  decinit_kernel<<<dim3(96), dim3(256), 0, stream>>>(fa + F_DECINIT, bfa + WB_STATE);

  decoder_kernel<<<dim3(16), dim3(1024), 0, stream>>>(
      fa + F_XG_D, fa + F_DCONST, bfa + WB_WHH_D, bfa + WB_WIH_D, bfa + WB_WRO,
      W_trg, b_trg, w_att, b_att, fa + F_XENCK, bfa + WB_XENC, fa + F_DECINIT,
      bfa + WB_STATE, fa + F_PROJP, bfa + WB_PRES, barriers);

  // G7: logits = pres @ W_read^T, permuted to (B, T, V)
  gemm_bt<<<dim3(16 * 250), dim3(256), 0, stream>>>(
      bfa + WB_PRES, bfa + WB_WRD, out, 32000, 512, 512, 512,
      nullptr, nullptr, 1, 2048);
}